// Round 10
// baseline (194.753 us; speedup 1.0000x reference)
//
#include <hip/hip_runtime.h>
#include <hip/hip_bf16.h>

// ---------------- common ----------------
typedef __attribute__((ext_vector_type(4))) int i32x4;
typedef __attribute__((ext_vector_type(16))) int i32x16;

#define M_DIM 8192
#define N_DIM 4096
#define K_DIM 4096
#define BM 256
#define BN 256
#define BK 128
#define NT2 (K_DIM / BK)  // 32

static __device__ inline void gload_lds16(const void* g, void* l) {
  __builtin_amdgcn_global_load_lds(
      (const __attribute__((address_space(1))) unsigned int*)g,
      (__attribute__((address_space(3))) unsigned int*)l,
      16, 0, 0);
}

// ---------------- prep: x fp32 -> i8 (per-row symmetric), row scale + int row-sum ----------------
__global__ __launch_bounds__(256) void prep_x_i8(
    const float* __restrict__ x, char* __restrict__ xq,
    float* __restrict__ rx, float* __restrict__ sxf) {
  const int row = blockIdx.x;
  const int tid = threadIdx.x;
  const float4* xr = (const float4*)(x + (long)row * K_DIM);
  float4 v[4];
  float mx = 0.f;
#pragma unroll
  for (int i = 0; i < 4; ++i) {
    v[i] = xr[i * 256 + tid];
    mx = fmaxf(mx, fmaxf(fmaxf(fabsf(v[i].x), fabsf(v[i].y)),
                         fmaxf(fabsf(v[i].z), fabsf(v[i].w))));
  }
#pragma unroll
  for (int off = 32; off > 0; off >>= 1) mx = fmaxf(mx, __shfl_down(mx, off, 64));
  __shared__ float redm[4];
  __shared__ int reds[4];
  const int lane = tid & 63, w = tid >> 6;
  if (lane == 0) redm[w] = mx;
  __syncthreads();
  const float maxv = fmaxf(fmaxf(redm[0], redm[1]), fmaxf(redm[2], redm[3]));
  const float inv = maxv > 0.f ? 127.f / maxv : 0.f;
  int* xo = (int*)(xq + (long)row * K_DIM);
  int ssum = 0;
#pragma unroll
  for (int i = 0; i < 4; ++i) {
    const int q0 = __float2int_rn(v[i].x * inv);
    const int q1 = __float2int_rn(v[i].y * inv);
    const int q2 = __float2int_rn(v[i].z * inv);
    const int q3 = __float2int_rn(v[i].w * inv);
    ssum += q0 + q1 + q2 + q3;
    xo[i * 256 + tid] =
        (q0 & 255) | ((q1 & 255) << 8) | ((q2 & 255) << 16) | ((q3 & 255) << 24);
  }
#pragma unroll
  for (int off = 32; off > 0; off >>= 1) ssum += __shfl_down(ssum, off, 64);
  if (lane == 0) reds[w] = ssum;
  __syncthreads();
  if (tid == 0) {
    rx[row] = maxv * (1.f / 127.f);
    sxf[row] = (float)(reds[0] + reds[1] + reds[2] + reds[3]);
  }
}

// ---------------- prep: qweight int32 [0,255] -> i8 (q-128), exact ----------------
__global__ __launch_bounds__(256) void prep_q_i8(
    const int* __restrict__ q, char* __restrict__ qb) {
  const long idx = (long)blockIdx.x * blockDim.x + threadIdx.x;  // one int4 -> one int
  const int4 v = ((const int4*)q)[idx];
  const int a = v.x - 128, b = v.y - 128, c = v.z - 128, d = v.w - 128;
  ((int*)qb)[idx] = (a & 255) | ((b & 255) << 8) | ((c & 255) << 16) | ((d & 255) << 24);
}

// ---------------- GEMM: 256x256, BK=128, i8 32x32x32 MFMA, register-prefetch pipeline ----------------
// R9 geometry (conflict-free 128B rows, XOR-(row&7) chunk swizzle both-sides) with
// ds_reads REGISTER-PREFETCHED one half-tile ahead so the LDS pipe runs under the
// matrix pipe:
//   frag groups: fa = A fm{0,1} (8 b128), ga = A fm{2,3} (8), vb = B (8).
//   phase A of t: stage ALL of tile t+1 (8 loads); VMC(8)+BAR (G2(t) landed,
//     collective); read ga(t); half1 MFMA (uses fa,vb — in regs, reads hide).
//   phase B of t: lgkmcnt(0) (ga done -> buf[t-1] overwrite safe); VMC(2)+BAR
//     (G1(t+1) landed, collective); read fa(t+1); half2 MFMA (uses ga,vb — reads
//     hide); read vb(t+1) (hides under loop-head staging/VMC/BAR).
// Ledger: phase A in-flight = G2(t){2} + G(t+1){8} = 10 -> VMC(8) forces G2(t).
//         phase B in-flight = G(t+1){8} -> VMC(2) forces G1(t+1) = {A0,A2,B*} which
//         is exactly what fa/vb(t+1) read. G2 is a full tile deep (HBM latency).
__global__ __launch_bounds__(512, 2) void wq_gemm_i8(
    const char* __restrict__ A,             // xq [M][K] i8
    const char* __restrict__ B,             // qb [N][K] i8
    const float* __restrict__ rx,           // [M] row scale
    const float* __restrict__ sxf,          // [M] sum of xi (float, exact)
    const float* __restrict__ scales,       // [N]
    const float* __restrict__ zps,          // [N]
    const float* __restrict__ bias,         // [N]
    float* __restrict__ C) {                // [M][N]
  __shared__ __align__(16) char lds[2 * 65536];  // [buf][A:32KB | B:32KB]

  const int tid = threadIdx.x;
  const int lane = tid & 63;
  const int wv = tid >> 6;
  const int wr = wv >> 2, wc = wv & 3;

  // T1: XCD-aware chunked swizzle (nwg=512, 512%8==0).
  const int wg = blockIdx.x;
  const int lid = (wg & 7) * 64 + (wg >> 3);
  const int bx = lid & 15, by = lid >> 4;
  const int brow = by * BM;
  const int bcol = bx * BN;

  i32x16 acc[4][2] = {};

  // ---- staging: sweep = 512 thr x 16B = 8KB = 64 rows x 128B; 4 sweeps per matrix ----
  const int srow = tid >> 3;                           // 0..63 within sweep
  const int schunk = ((tid & 7) ^ (srow & 7)) * 16;    // pre-swizzled source chunk
  const int wub = (tid & ~63) * 16;                    // wave-uniform LDS base
  const char* gAs = A + (long)(brow + srow) * K_DIM + schunk;
  const char* gBs = B + (long)(bcol + srow) * K_DIM + schunk;

#define STAGE_A2(T, J0, J1)                                                   \
  do {                                                                        \
    char* d = lds + ((T) & 1) * 65536;                                        \
    gload_lds16(gAs + (long)(J0) * 262144 + (long)(T) * 128,                  \
                d + (J0) * 8192 + wub);                                       \
    gload_lds16(gAs + (long)(J1) * 262144 + (long)(T) * 128,                  \
                d + (J1) * 8192 + wub);                                       \
  } while (0)
#define STAGE_B2(T, J0, J1)                                                   \
  do {                                                                        \
    char* d = lds + ((T) & 1) * 65536 + 32768;                                \
    gload_lds16(gBs + (long)(J0) * 262144 + (long)(T) * 128,                  \
                d + (J0) * 8192 + wub);                                       \
    gload_lds16(gBs + (long)(J1) * 262144 + (long)(T) * 128,                  \
                d + (J1) * 8192 + wub);                                       \
  } while (0)

  // ---- fragment read offsets ----
  // 32x32x32 i8 operand: lane holds [row=lane&31][k = kg*16 + 0..15], kg=lane>>5.
  // Within a 128B row: chunk(ks) = ks*2 + kg (ks=0..3), swizzled by XOR (row&7).
  const int row5 = lane & 31;
  const int kg = lane >> 5;
  int aoff[4];
#pragma unroll
  for (int ks = 0; ks < 4; ++ks) {
    const int ch = ((ks * 2 + kg) ^ (row5 & 7)) * 16;
    aoff[ks] = (wr * 128 + row5) * 128 + ch;
  }
  const int bdiff = (wc * 64 - wr * 128) * 128 + 32768;  // boff[ks] = aoff[ks] + bdiff

#define RD_A(BB, FM, KS) (*(const i32x4*)(lds + (BB) + aoff[KS] + (FM) * 4096))
#define RD_B(BB, FN, KS) (*(const i32x4*)(lds + (BB) + aoff[KS] + bdiff + (FN) * 4096))
#define MMA(FM, FN, AV, BV)                                                   \
  acc[FM][FN] = __builtin_amdgcn_mfma_i32_32x32x32_i8(AV, BV, acc[FM][FN], 0, 0, 0)

#define BAR() __builtin_amdgcn_s_barrier()
#define VMC(N)                                                                \
  do {                                                                        \
    asm volatile("s_waitcnt vmcnt(" #N ")");                                  \
    __builtin_amdgcn_sched_barrier(0);                                        \
  } while (0)
#define LGK0()                                                                \
  do {                                                                        \
    asm volatile("s_waitcnt lgkmcnt(0)");                                     \
    __builtin_amdgcn_sched_barrier(0);                                        \
  } while (0)
#define SCHED() __builtin_amdgcn_sched_barrier(0)

  i32x4 fa00, fa01, fa02, fa03, fa10, fa11, fa12, fa13;  // A fm{0,1} x ks
  i32x4 ga00, ga01, ga02, ga03, ga10, ga11, ga12, ga13;  // A fm{2,3} x ks
  i32x4 vb00, vb01, vb02, vb03, vb10, vb11, vb12, vb13;  // B fn{0,1} x ks

  // ---- prologue: stage tile 0 (G1 then G2 order); read fa/vb(0) ----
  STAGE_A2(0, 0, 2);
  STAGE_B2(0, 0, 2);
  STAGE_B2(0, 1, 3);
  STAGE_A2(0, 1, 3);
  VMC(2);  // G1(0) = {A0,A2,B*} landed; G2(0)={A1,A3} still flying
  BAR();
  fa00 = RD_A(0, 0, 0); fa01 = RD_A(0, 0, 1); fa02 = RD_A(0, 0, 2); fa03 = RD_A(0, 0, 3);
  fa10 = RD_A(0, 1, 0); fa11 = RD_A(0, 1, 1); fa12 = RD_A(0, 1, 2); fa13 = RD_A(0, 1, 3);
  vb00 = RD_B(0, 0, 0); vb01 = RD_B(0, 0, 1); vb02 = RD_B(0, 0, 2); vb03 = RD_B(0, 0, 3);
  vb10 = RD_B(0, 1, 0); vb11 = RD_B(0, 1, 1); vb12 = RD_B(0, 1, 2); vb13 = RD_B(0, 1, 3);

  // ---- main loop: tiles 0..NT2-2 ----
  for (int t = 0; t < NT2 - 1; ++t) {
    const int bb = (t & 1) * 65536;
    const int nb = bb ^ 65536;
    const int t1 = t + 1;
    // ---- phase A ----
    STAGE_A2(t1, 0, 2);      // G1(t+1): 6 loads
    STAGE_B2(t1, 0, 2);
    STAGE_B2(t1, 1, 3);
    STAGE_A2(t1, 1, 3);      // G2(t+1): 2 loads (full tile deep)
    VMC(8);                  // forces G2(t) = {A1,A3} of tile t (own)
    BAR();                   // collective: all waves' G2(t) landed
    ga00 = RD_A(bb, 2, 0); ga01 = RD_A(bb, 2, 1); ga02 = RD_A(bb, 2, 2); ga03 = RD_A(bb, 2, 3);
    ga10 = RD_A(bb, 3, 0); ga11 = RD_A(bb, 3, 1); ga12 = RD_A(bb, 3, 2); ga13 = RD_A(bb, 3, 3);
    SCHED();
    __builtin_amdgcn_s_setprio(1);
    // half1: fm {0,1} (fa, vb in regs; ga reads execute underneath)
    MMA(0, 0, fa00, vb00); MMA(0, 1, fa00, vb10);
    MMA(1, 0, fa10, vb00); MMA(1, 1, fa10, vb10);
    MMA(0, 0, fa01, vb01); MMA(0, 1, fa01, vb11);
    MMA(1, 0, fa11, vb01); MMA(1, 1, fa11, vb11);
    MMA(0, 0, fa02, vb02); MMA(0, 1, fa02, vb12);
    MMA(1, 0, fa12, vb02); MMA(1, 1, fa12, vb12);
    MMA(0, 0, fa03, vb03); MMA(0, 1, fa03, vb13);
    MMA(1, 0, fa13, vb03); MMA(1, 1, fa13, vb13);
    __builtin_amdgcn_s_setprio(0);
    // ---- phase B ----
    LGK0();                  // ga reads done -> next G1 overwrite of old buf safe
    VMC(2);                  // forces G1(t+1) = {A0,A2,B*} (own)
    BAR();                   // collective: all waves' G1(t+1) landed
    fa00 = RD_A(nb, 0, 0); fa01 = RD_A(nb, 0, 1); fa02 = RD_A(nb, 0, 2); fa03 = RD_A(nb, 0, 3);
    fa10 = RD_A(nb, 1, 0); fa11 = RD_A(nb, 1, 1); fa12 = RD_A(nb, 1, 2); fa13 = RD_A(nb, 1, 3);
    SCHED();
    __builtin_amdgcn_s_setprio(1);
    // half2: fm {2,3} (ga, vb in regs; fa(t+1) reads execute underneath)
    MMA(2, 0, ga00, vb00); MMA(2, 1, ga00, vb10);
    MMA(3, 0, ga10, vb00); MMA(3, 1, ga10, vb10);
    MMA(2, 0, ga01, vb01); MMA(2, 1, ga01, vb11);
    MMA(3, 0, ga11, vb01); MMA(3, 1, ga11, vb11);
    MMA(2, 0, ga02, vb02); MMA(2, 1, ga02, vb12);
    MMA(3, 0, ga12, vb02); MMA(3, 1, ga12, vb12);
    MMA(2, 0, ga03, vb03); MMA(2, 1, ga03, vb13);
    MMA(3, 0, ga13, vb03); MMA(3, 1, ga13, vb13);
    __builtin_amdgcn_s_setprio(0);
    // vb(t) dead -> read vb(t+1); hides under loop-head staging/VMC/BAR
    vb00 = RD_B(nb, 0, 0); vb01 = RD_B(nb, 0, 1); vb02 = RD_B(nb, 0, 2); vb03 = RD_B(nb, 0, 3);
    vb10 = RD_B(nb, 1, 0); vb11 = RD_B(nb, 1, 1); vb12 = RD_B(nb, 1, 2); vb13 = RD_B(nb, 1, 3);
  }

  // ---- tail: tile NT2-1 (buf1), no staging ----
  {
    const int bb = 65536;
    VMC(0);                  // only G2(NT2-1) in flight
    BAR();                   // collective
    ga00 = RD_A(bb, 2, 0); ga01 = RD_A(bb, 2, 1); ga02 = RD_A(bb, 2, 2); ga03 = RD_A(bb, 2, 3);
    ga10 = RD_A(bb, 3, 0); ga11 = RD_A(bb, 3, 1); ga12 = RD_A(bb, 3, 2); ga13 = RD_A(bb, 3, 3);
    SCHED();
    MMA(0, 0, fa00, vb00); MMA(0, 1, fa00, vb10);
    MMA(1, 0, fa10, vb00); MMA(1, 1, fa10, vb10);
    MMA(0, 0, fa01, vb01); MMA(0, 1, fa01, vb11);
    MMA(1, 0, fa11, vb01); MMA(1, 1, fa11, vb11);
    MMA(0, 0, fa02, vb02); MMA(0, 1, fa02, vb12);
    MMA(1, 0, fa12, vb02); MMA(1, 1, fa12, vb12);
    MMA(0, 0, fa03, vb03); MMA(0, 1, fa03, vb13);
    MMA(1, 0, fa13, vb03); MMA(1, 1, fa13, vb13);
    MMA(2, 0, ga00, vb00); MMA(2, 1, ga00, vb10);
    MMA(3, 0, ga10, vb00); MMA(3, 1, ga10, vb10);
    MMA(2, 0, ga01, vb01); MMA(2, 1, ga01, vb11);
    MMA(3, 0, ga11, vb01); MMA(3, 1, ga11, vb11);
    MMA(2, 0, ga02, vb02); MMA(2, 1, ga02, vb12);
    MMA(3, 0, ga12, vb02); MMA(3, 1, ga12, vb12);
    MMA(2, 0, ga03, vb03); MMA(2, 1, ga03, vb13);
    MMA(3, 0, ga13, vb03); MMA(3, 1, ga13, vb13);
  }

  // ---- epilogue: C/D layout col=lane&31, row=(r&3)+8*(r>>2)+4*kg (dtype-indep) ----
  // y = s * rx * (dot_i32 + (128 - zp) * sum_xi) + b
  float sc[2], zp[2], bs[2];
  int coln[2];
#pragma unroll
  for (int fn = 0; fn < 2; ++fn) {
    coln[fn] = bcol + wc * 64 + fn * 32 + row5;
    sc[fn] = scales[coln[fn]];
    zp[fn] = 128.f - zps[coln[fn]];
    bs[fn] = bias[coln[fn]];
  }
#pragma unroll
  for (int fm = 0; fm < 4; ++fm) {
#pragma unroll
    for (int r = 0; r < 16; ++r) {
      const int grow = brow + wr * 128 + fm * 32 + (r & 3) + 8 * (r >> 2) + 4 * kg;
      const float rxv = rx[grow];
      const float sxv = sxf[grow];
#pragma unroll
      for (int fn = 0; fn < 2; ++fn) {
        C[(long)grow * N_DIM + coln[fn]] =
            sc[fn] * rxv * ((float)acc[fm][fn][r] + zp[fn] * sxv) + bs[fn];
      }
    }
  }
}

// ---------------- launch ----------------
extern "C" void kernel_launch(void* const* d_in, const int* in_sizes, int n_in,
                              void* d_out, int out_size, void* d_ws, size_t ws_size,
                              hipStream_t stream) {
  const float* x = (const float*)d_in[0];
  const int* qw = (const int*)d_in[1];
  const float* scales = (const float*)d_in[2];
  const float* zps = (const float*)d_in[3];
  const float* bias = (const float*)d_in[4];
  float* out = (float*)d_out;

  char* ws = (char*)d_ws;
  char* xq = ws;                                             // 32 MB i8
  char* qb = ws + (size_t)32 * 1024 * 1024;                  // 16 MB i8
  float* rx = (float*)(ws + (size_t)48 * 1024 * 1024);       // 32 KB
  float* sxf = (float*)(ws + (size_t)48 * 1024 * 1024 + 65536);  // 32 KB

  hipLaunchKernelGGL(prep_x_i8, dim3(M_DIM), dim3(256), 0, stream, x, xq, rx, sxf);
  hipLaunchKernelGGL(prep_q_i8, dim3((N_DIM * K_DIM / 4) / 256), dim3(256), 0, stream,
                     qw, qb);
  hipLaunchKernelGGL(wq_gemm_i8, dim3((M_DIM / BM) * (N_DIM / BN)), dim3(512), 0,
                     stream, xq, qb, rx, sxf, scales, zps, bias, out);
}